// Round 2
// baseline (2523.194 us; speedup 1.0000x reference)
//
#include <hip/hip_runtime.h>
#include <hip/hip_bf16.h>

// Mamba block: B=8 L=2048 D_MODEL=1024 D_INNER=2048 D_STATE=16 D_CONV=4 DT_RANK=64
#define LB 2048
#define DM 1024
#define EE 2048
#define RP 128   // x_dbl padded width (64 dt_r + 16 B + 16 C + 32 pad)

typedef __attribute__((ext_vector_type(8))) short bf16x8;
typedef __attribute__((ext_vector_type(4))) float f32x4;
using bf16 = __hip_bfloat16;

__device__ __forceinline__ float b2f(bf16 v){ return __bfloat162float(v); }
__device__ __forceinline__ bf16 f2b(float v){ return __float2bfloat16(v); }

// ---------------- cast helpers ----------------
__global__ void cast_kernel(const float* __restrict__ s, bf16* __restrict__ d, int n){
  int i = blockIdx.x*256 + threadIdx.x;
  int st = gridDim.x*256;
  for(; i<n; i+=st) d[i] = f2b(s[i]);
}

__global__ void pad_xproj_kernel(const float* __restrict__ s, bf16* __restrict__ d){
  int i = blockIdx.x*256 + threadIdx.x;  // over 128*2048
  int row = i >> 11;
  int col = i & 2047;
  float v = (row < 96) ? s[row*2048 + col] : 0.f;
  d[i] = f2b(v);
}

// ---------------- layernorm -> bf16 ----------------
__device__ __forceinline__ float wave_sum(float v){
  #pragma unroll
  for (int m=32;m>=1;m>>=1) v += __shfl_xor(v, m, 64);
  return v;
}

__global__ __launch_bounds__(256) void ln_kernel(const float* __restrict__ x,
                                                 const float* __restrict__ w,
                                                 const float* __restrict__ bb,
                                                 bf16* __restrict__ h){
  long row = blockIdx.x;
  const float4* xr = (const float4*)(x + row*DM);
  float4 v = xr[threadIdx.x];
  float s1 = v.x+v.y+v.z+v.w;
  float s2 = v.x*v.x+v.y*v.y+v.z*v.z+v.w*v.w;
  __shared__ float sm1[4], sm2[4];
  float w1 = wave_sum(s1), w2 = wave_sum(s2);
  int wid = threadIdx.x>>6, lane = threadIdx.x&63;
  if (lane==0){ sm1[wid]=w1; sm2[wid]=w2; }
  __syncthreads();
  float t1 = sm1[0]+sm1[1]+sm1[2]+sm1[3];
  float t2 = sm2[0]+sm2[1]+sm2[2]+sm2[3];
  float mean = t1 * (1.f/(float)DM);
  float var  = t2 * (1.f/(float)DM) - mean*mean;
  float rs = rsqrtf(var + 1e-5f);
  float4 wv = ((const float4*)w)[threadIdx.x];
  float4 bv = ((const float4*)bb)[threadIdx.x];
  int col = threadIdx.x*4;
  bf16 tmp[4];
  tmp[0] = f2b((v.x-mean)*rs*wv.x + bv.x);
  tmp[1] = f2b((v.y-mean)*rs*wv.y + bv.y);
  tmp[2] = f2b((v.z-mean)*rs*wv.z + bv.z);
  tmp[3] = f2b((v.w-mean)*rs*wv.w + bv.w);
  *(ushort4*)(h + row*DM + col) = *(ushort4*)tmp;
}

// ---------------- GEMM: C(MxN) = A(MxK) * Bw(NxK)^T, bf16 in, fp32 acc ----------------
// MODE 0: store bf16.
// MODE 1: softplus(acc+bias[col]) -> bf16.
// MODE 2: acc+resid -> fp32.
// MODE 3: split store: col<2048 -> Cout[row*2048+col], else Cout2[row*2048+col-2048] (bf16)
template<int MODE>
__global__ __launch_bounds__(256) void gemm_bt(
  const bf16* __restrict__ A, int lda,
  const bf16* __restrict__ Bw, int ldb,
  void* __restrict__ Cout, int ldc,
  int K,
  const float* __restrict__ bias,
  const float* __restrict__ resid, int ldr,
  void* __restrict__ Cout2)
{
  int wid  = threadIdx.x >> 6;
  int lane = threadIdx.x & 63;
  int wr = wid >> 1, wc = wid & 1;           // 2x2 waves -> 128x128 block tile
  int bm = blockIdx.y*128 + wr*64;
  int bn = blockIdx.x*128 + wc*64;
  int lm = lane & 15;                         // row within fragment
  int kg = lane >> 4;                         // k-group, k offset kg*8
  f32x4 acc[4][4] = {};
  const bf16* Ab = A  + (long)(bm+lm)*lda + kg*8;
  const bf16* Bb = Bw + (long)(bn+lm)*ldb + kg*8;
  for (int k0 = 0; k0 < K; k0 += 32){
    bf16x8 a[4], b[4];
    #pragma unroll
    for (int i=0;i<4;i++) a[i] = *(const bf16x8*)(Ab + (long)i*16*lda + k0);
    #pragma unroll
    for (int j=0;j<4;j++) b[j] = *(const bf16x8*)(Bb + (long)j*16*ldb + k0);
    #pragma unroll
    for (int i=0;i<4;i++)
      #pragma unroll
      for (int j=0;j<4;j++)
        acc[i][j] = __builtin_amdgcn_mfma_f32_16x16x32_bf16(a[i], b[j], acc[i][j], 0,0,0);
  }
  #pragma unroll
  for (int i=0;i<4;i++)
    #pragma unroll
    for (int j=0;j<4;j++)
      #pragma unroll
      for (int r=0;r<4;r++){
        int row = bm + i*16 + kg*4 + r;
        int col = bn + j*16 + lm;
        float v = acc[i][j][r];
        if constexpr (MODE==0){
          ((bf16*)Cout)[(long)row*ldc + col] = f2b(v);
        } else if constexpr (MODE==1){
          float t = v + bias[col];
          float sp = (t > 15.f) ? t : log1pf(__expf(t));
          ((bf16*)Cout)[(long)row*ldc + col] = f2b(sp);
        } else if constexpr (MODE==2){
          ((float*)Cout)[(long)row*ldc + col] = v + resid[(long)row*ldr + col];
        } else {
          if (col < EE) ((bf16*)Cout )[(long)row*EE + col]      = f2b(v);
          else          ((bf16*)Cout2)[(long)row*EE + col - EE] = f2b(v);
        }
      }
}

// ---------------- depthwise causal conv(4) + SiLU ----------------
__global__ __launch_bounds__(256) void conv_silu_kernel(
  const bf16* __restrict__ xraw,   // (B,L,E)
  const float* __restrict__ cw,    // (E,1,4)
  const float* __restrict__ cb,    // (E)
  bf16* __restrict__ out)          // (B,L,E)
{
  long idx = (long)blockIdx.x*256 + threadIdx.x;   // over 8*2048*2048
  int e = idx & (EE-1);
  long bl = idx >> 11;
  int l = bl & (LB-1);
  long b = bl >> 11;
  float acc = cb[e];
  #pragma unroll
  for (int k=0;k<4;k++){
    int ls = l - 3 + k;
    if (ls >= 0)
      acc += b2f(xraw[((b*LB)+ls)*EE + e]) * cw[e*4 + k];
  }
  float s = acc / (1.f + __expf(-acc));
  out[idx] = f2b(s);
}

// ---------------- selective scan + gating ----------------
// thread layout: n = tid&15 (state index), e = blockIdx.x*16 + (tid>>4), b = blockIdx.y
// zy: z is read at (b,l,e) and y written at (b,l,e) through the SAME pointer (in-place).
__global__ __launch_bounds__(256) void scan_kernel(
  const bf16* __restrict__ dt,     // (B,L,E)
  const bf16* __restrict__ xm,     // (B,L,E)
  const bf16* __restrict__ xdbl,   // (B,L,128): cols [64,80)=B, [80,96)=C
  bf16* zy,                        // (B,L,E): in z, out y (in-place)
  const float* __restrict__ A_log, // (E,16)
  const float* __restrict__ Dp)    // (E)
{
  int t = threadIdx.x;
  int n  = t & 15;
  int le = t >> 4;
  int e = blockIdx.x*16 + le;
  int b = blockIdx.y;
  float An = -expf(A_log[e*16 + n]);
  float Dv = Dp[e];
  float hs = 0.f;
  long base = ((long)b*LB)*EE + e;        // step stride EE
  long base_xd = ((long)b*LB)*RP;         // step stride RP
  // prefetch l=0
  float dtv = b2f(dt[base]);
  float xv  = b2f(xm[base]);
  float Bn  = b2f(xdbl[base_xd + 64 + n]);
  float Cn  = b2f(xdbl[base_xd + 80 + n]);
  for (int l = 0; l < LB; ++l){
    float dtc=dtv, xc=xv, Bc=Bn, Cc=Cn;
    if (l+1 < LB){
      long o = base + (long)(l+1)*EE;
      dtv = b2f(dt[o]);
      xv  = b2f(xm[o]);
      long o2 = base_xd + (long)(l+1)*RP;
      Bn = b2f(xdbl[o2 + 64 + n]);
      Cn = b2f(xdbl[o2 + 80 + n]);
    }
    float dA = __expf(dtc * An);
    hs = dA*hs + (dtc*xc)*Bc;
    float ys = hs * Cc;
    ys += __shfl_xor(ys, 1, 64);
    ys += __shfl_xor(ys, 2, 64);
    ys += __shfl_xor(ys, 4, 64);
    ys += __shfl_xor(ys, 8, 64);
    if (n == 0){
      long o = base + (long)l*EE;
      float zv = b2f(zy[o]);
      float g = zv / (1.f + __expf(-zv));
      zy[o] = f2b((ys + xc*Dv) * g);
    }
  }
}

extern "C" void kernel_launch(void* const* d_in, const int* in_sizes, int n_in,
                              void* d_out, int out_size, void* d_ws, size_t ws_size,
                              hipStream_t stream) {
  const float* x       = (const float*)d_in[0];
  const float* ln_w    = (const float*)d_in[1];
  const float* ln_b    = (const float*)d_in[2];
  const float* w_in_f  = (const float*)d_in[3];
  const float* conv_w  = (const float*)d_in[4];
  const float* conv_b  = (const float*)d_in[5];
  const float* w_xp_f  = (const float*)d_in[6];
  const float* w_dt_f  = (const float*)d_in[7];
  const float* dt_bias = (const float*)d_in[8];
  const float* A_log   = (const float*)d_in[9];
  const float* Dp      = (const float*)d_in[10];
  const float* w_out_f = (const float*)d_in[11];
  float* out = (float*)d_out;

  // Workspace layout (177 MiB total; lifetimes annotated):
  char* p = (char*)d_ws;
  bf16* h_bf  = (bf16*)p; p += (size_t)16384*1024*2;   // 32 MiB  [ln -> in_proj]
  bf16* xraw  = (bf16*)p; p += (size_t)16384*2048*2;   // 64 MiB  [in_proj -> conv]; then dt [dt_proj -> scan]
  bf16* zbuf  = (bf16*)p; p += (size_t)16384*2048*2;   // 64 MiB  [in_proj -> scan]; scan writes y in-place
  bf16* xdbl  = (bf16*)p; p += (size_t)16384*128*2;    // 4 MiB   [x_proj -> scan]
  bf16* w_in  = (bf16*)p; p += (size_t)4096*1024*2;    // 8 MiB
  bf16* w_xp  = (bf16*)p; p += (size_t)128*2048*2;     // 0.5 MiB
  bf16* w_dt  = (bf16*)p; p += (size_t)2048*64*2;      // 0.25 MiB
  bf16* w_out = (bf16*)p; p += (size_t)1024*2048*2;    // 4 MiB
  bf16* dt    = xraw;                                   // alias: xraw dead after conv
  bf16* xm    = (bf16*)d_out;                           // 64 MiB scratch in d_out: dead before out_proj writes

  // weight casts
  cast_kernel<<<16384,256,0,stream>>>(w_in_f,  w_in, 4096*1024);
  cast_kernel<<<512,  256,0,stream>>>(w_dt_f,  w_dt, 2048*64);
  cast_kernel<<<8192, 256,0,stream>>>(w_out_f, w_out, 1024*2048);
  pad_xproj_kernel<<<1024,256,0,stream>>>(w_xp_f, w_xp);

  // layernorm
  ln_kernel<<<16384,256,0,stream>>>(x, ln_w, ln_b, h_bf);

  // in_proj: (16384x1024) x (4096x1024)^T -> xraw (cols<2048) + zbuf (cols>=2048)
  gemm_bt<3><<<dim3(32,128),256,0,stream>>>(h_bf,1024, w_in,1024, xraw,EE, 1024, nullptr, nullptr,0, zbuf);

  // conv + silu -> xm (in d_out)
  conv_silu_kernel<<<131072,256,0,stream>>>(xraw, conv_w, conv_b, xm);

  // x_proj: (16384x2048) x (128x2048)^T -> xdbl bf16 (padded)
  gemm_bt<0><<<dim3(1,128),256,0,stream>>>(xm,2048, w_xp,2048, xdbl,RP, 2048, nullptr, nullptr,0, nullptr);

  // dt_proj + softplus: (16384x64) x (2048x64)^T -> dt (overlays xraw)
  gemm_bt<1><<<dim3(16,128),256,0,stream>>>(xdbl,RP, w_dt,64, dt,EE, 64, dt_bias, nullptr,0, nullptr);

  // selective scan + gating: reads dt, xm, xdbl, z; writes y in-place over z
  scan_kernel<<<dim3(128,8),256,0,stream>>>(dt, xm, xdbl, zbuf, A_log, Dp);

  // out_proj + residual: (16384x2048) x (1024x2048)^T + x -> out fp32 (overwrites xm scratch)
  gemm_bt<2><<<dim3(8,128),256,0,stream>>>(zbuf,2048, w_out,2048, out,1024, 2048, nullptr, x,1024, nullptr);
}

// Round 3
// 2154.789 us; speedup vs baseline: 1.1710x; 1.1710x over previous
//
#include <hip/hip_runtime.h>
#include <hip/hip_bf16.h>

// Mamba block: B=8 L=2048 D_MODEL=1024 D_INNER=2048 D_STATE=16 D_CONV=4 DT_RANK=64
#define LB 2048
#define DM 1024
#define EE 2048
#define RP 128   // x_dbl padded width (64 dt_r + 16 B + 16 C + 32 pad)
#define CH 128   // scan chunk length
#define NC 16    // LB/CH chunks

typedef __attribute__((ext_vector_type(8))) short bf16x8;
typedef __attribute__((ext_vector_type(4))) float f32x4;
using bf16 = __hip_bfloat16;

__device__ __forceinline__ float b2f(bf16 v){ return __bfloat162float(v); }
__device__ __forceinline__ bf16 f2b(float v){ return __float2bfloat16(v); }

// ---------------- cast helpers ----------------
__global__ void cast_kernel(const float* __restrict__ s, bf16* __restrict__ d, int n){
  int i = blockIdx.x*256 + threadIdx.x;
  int st = gridDim.x*256;
  for(; i<n; i+=st) d[i] = f2b(s[i]);
}

__global__ void pad_xproj_kernel(const float* __restrict__ s, bf16* __restrict__ d){
  int i = blockIdx.x*256 + threadIdx.x;  // over 128*2048
  int row = i >> 11;
  int col = i & 2047;
  float v = (row < 96) ? s[row*2048 + col] : 0.f;
  d[i] = f2b(v);
}

// ---------------- layernorm -> bf16 ----------------
__device__ __forceinline__ float wave_sum(float v){
  #pragma unroll
  for (int m=32;m>=1;m>>=1) v += __shfl_xor(v, m, 64);
  return v;
}

__global__ __launch_bounds__(256) void ln_kernel(const float* __restrict__ x,
                                                 const float* __restrict__ w,
                                                 const float* __restrict__ bb,
                                                 bf16* __restrict__ h){
  long row = blockIdx.x;
  const float4* xr = (const float4*)(x + row*DM);
  float4 v = xr[threadIdx.x];
  float s1 = v.x+v.y+v.z+v.w;
  float s2 = v.x*v.x+v.y*v.y+v.z*v.z+v.w*v.w;
  __shared__ float sm1[4], sm2[4];
  float w1 = wave_sum(s1), w2 = wave_sum(s2);
  int wid = threadIdx.x>>6, lane = threadIdx.x&63;
  if (lane==0){ sm1[wid]=w1; sm2[wid]=w2; }
  __syncthreads();
  float t1 = sm1[0]+sm1[1]+sm1[2]+sm1[3];
  float t2 = sm2[0]+sm2[1]+sm2[2]+sm2[3];
  float mean = t1 * (1.f/(float)DM);
  float var  = t2 * (1.f/(float)DM) - mean*mean;
  float rs = rsqrtf(var + 1e-5f);
  float4 wv = ((const float4*)w)[threadIdx.x];
  float4 bv = ((const float4*)bb)[threadIdx.x];
  int col = threadIdx.x*4;
  bf16 tmp[4];
  tmp[0] = f2b((v.x-mean)*rs*wv.x + bv.x);
  tmp[1] = f2b((v.y-mean)*rs*wv.y + bv.y);
  tmp[2] = f2b((v.z-mean)*rs*wv.z + bv.z);
  tmp[3] = f2b((v.w-mean)*rs*wv.w + bv.w);
  *(ushort4*)(h + row*DM + col) = *(ushort4*)tmp;
}

// ---------------- GEMM: C(MxN) = A(MxK) * Bw(NxK)^T, bf16 in, fp32 acc ----------------
// MODE 0: store bf16.
// MODE 1: softplus(acc+bias[col]) -> bf16.
// MODE 2: acc+resid -> fp32.
// MODE 3: split store: col<2048 -> Cout, else Cout2 (both bf16, ld 2048)
template<int MODE>
__global__ __launch_bounds__(256) void gemm_bt(
  const bf16* __restrict__ A, int lda,
  const bf16* __restrict__ Bw, int ldb,
  void* __restrict__ Cout, int ldc,
  int K,
  const float* __restrict__ bias,
  const float* __restrict__ resid, int ldr,
  void* __restrict__ Cout2)
{
  int wid  = threadIdx.x >> 6;
  int lane = threadIdx.x & 63;
  int wr = wid >> 1, wc = wid & 1;           // 2x2 waves -> 128x128 block tile
  int bm = blockIdx.y*128 + wr*64;
  int bn = blockIdx.x*128 + wc*64;
  int lm = lane & 15;                         // row within fragment
  int kg = lane >> 4;                         // k-group, k offset kg*8
  f32x4 acc[4][4] = {};
  const bf16* Ab = A  + (long)(bm+lm)*lda + kg*8;
  const bf16* Bb = Bw + (long)(bn+lm)*ldb + kg*8;
  for (int k0 = 0; k0 < K; k0 += 32){
    bf16x8 a[4], b[4];
    #pragma unroll
    for (int i=0;i<4;i++) a[i] = *(const bf16x8*)(Ab + (long)i*16*lda + k0);
    #pragma unroll
    for (int j=0;j<4;j++) b[j] = *(const bf16x8*)(Bb + (long)j*16*ldb + k0);
    #pragma unroll
    for (int i=0;i<4;i++)
      #pragma unroll
      for (int j=0;j<4;j++)
        acc[i][j] = __builtin_amdgcn_mfma_f32_16x16x32_bf16(a[i], b[j], acc[i][j], 0,0,0);
  }
  #pragma unroll
  for (int i=0;i<4;i++)
    #pragma unroll
    for (int j=0;j<4;j++)
      #pragma unroll
      for (int r=0;r<4;r++){
        int row = bm + i*16 + kg*4 + r;
        int col = bn + j*16 + lm;
        float v = acc[i][j][r];
        if constexpr (MODE==0){
          ((bf16*)Cout)[(long)row*ldc + col] = f2b(v);
        } else if constexpr (MODE==1){
          float t = v + bias[col];
          float sp = (t > 15.f) ? t : log1pf(__expf(t));
          ((bf16*)Cout)[(long)row*ldc + col] = f2b(sp);
        } else if constexpr (MODE==2){
          ((float*)Cout)[(long)row*ldc + col] = v + resid[(long)row*ldr + col];
        } else {
          if (col < EE) ((bf16*)Cout )[(long)row*EE + col]      = f2b(v);
          else          ((bf16*)Cout2)[(long)row*EE + col - EE] = f2b(v);
        }
      }
}

// ---------------- depthwise causal conv(4) + SiLU ----------------
__global__ __launch_bounds__(256) void conv_silu_kernel(
  const bf16* __restrict__ xraw,   // (B,L,E)
  const float* __restrict__ cw,    // (E,1,4)
  const float* __restrict__ cb,    // (E)
  bf16* __restrict__ out)          // (B,L,E)
{
  long idx = (long)blockIdx.x*256 + threadIdx.x;   // over 8*2048*2048
  int e = idx & (EE-1);
  long bl = idx >> 11;
  int l = bl & (LB-1);
  long b = bl >> 11;
  float acc = cb[e];
  #pragma unroll
  for (int k=0;k<4;k++){
    int ls = l - 3 + k;
    if (ls >= 0)
      acc += b2f(xraw[((b*LB)+ls)*EE + e]) * cw[e*4 + k];
  }
  float s = acc / (1.f + __expf(-acc));
  out[idx] = f2b(s);
}

// ---------------- chunked selective scan ----------------
// Pass 1: per (b, chunk, e, n): local state S (h0=0) and sum(dt) over chunk.
__global__ __launch_bounds__(256) void scan_pass1(
  const bf16* __restrict__ dt,     // (B,L,E)
  const bf16* __restrict__ xm,     // (B,L,E)
  const bf16* __restrict__ xdbl,   // (B,L,128): cols [64,80)=B
  const float* __restrict__ A_log, // (E,16)
  float* __restrict__ S,           // (B,NC,E,16)
  float* __restrict__ sdt)         // (B,NC,E)
{
  int t = threadIdx.x;
  int n  = t & 15;
  int le = t >> 4;
  int e = blockIdx.x*16 + le;
  int c = blockIdx.y;
  int b = blockIdx.z;
  float An = -expf(A_log[e*16 + n]);
  float hs = 0.f, sd = 0.f;
  long base    = ((long)b*LB + (long)c*CH)*EE + e;
  long base_xd = ((long)b*LB + (long)c*CH)*RP;
  for (int l = 0; l < CH; ++l){
    float dtc = b2f(dt[base + (long)l*EE]);
    float xc  = b2f(xm[base + (long)l*EE]);
    float Bc  = b2f(xdbl[base_xd + (long)l*RP + 64 + n]);
    float dA = __expf(dtc*An);
    hs = dA*hs + (dtc*xc)*Bc;
    sd += dtc;
  }
  long ci = ((long)b*NC + c)*EE + e;
  S[ci*16 + n] = hs;
  if (n == 0) sdt[ci] = sd;
}

// Pass 2: sequential scan over the NC chunk summaries; store exclusive prefix Hinit.
__global__ __launch_bounds__(256) void scan_pass2(
  const float* __restrict__ S,
  const float* __restrict__ sdt,
  const float* __restrict__ A_log,
  float* __restrict__ Hinit)       // (B,NC,E,16)
{
  int t = blockIdx.x*256 + threadIdx.x;   // over 8*2048*16
  int n = t & 15;
  int e = (t >> 4) & (EE-1);
  int b = t >> 15;
  float An = -expf(A_log[e*16 + n]);
  float H = 0.f;
  for (int c = 0; c < NC; ++c){
    long ci = ((long)b*NC + c)*EE + e;
    Hinit[ci*16 + n] = H;
    H = __expf(An * sdt[ci]) * H + S[ci*16 + n];
  }
}

// Pass 3: replay chunk with correct initial state; emit y (gated, in-place over z).
__global__ __launch_bounds__(256) void scan_pass3(
  const bf16* __restrict__ dt,
  const bf16* __restrict__ xm,
  const bf16* __restrict__ xdbl,   // cols [64,80)=B, [80,96)=C
  bf16* zy,                        // in z, out y (in-place, same pointer)
  const float* __restrict__ A_log,
  const float* __restrict__ Dp,
  const float* __restrict__ Hinit)
{
  int t = threadIdx.x;
  int n  = t & 15;
  int le = t >> 4;
  int e = blockIdx.x*16 + le;
  int c = blockIdx.y;
  int b = blockIdx.z;
  float An = -expf(A_log[e*16 + n]);
  float Dv = Dp[e];
  float hs = Hinit[(((long)b*NC + c)*EE + e)*16 + n];
  long base    = ((long)b*LB + (long)c*CH)*EE + e;
  long base_xd = ((long)b*LB + (long)c*CH)*RP;
  for (int l = 0; l < CH; ++l){
    float dtc = b2f(dt[base + (long)l*EE]);
    float xc  = b2f(xm[base + (long)l*EE]);
    float Bc  = b2f(xdbl[base_xd + (long)l*RP + 64 + n]);
    float Cc  = b2f(xdbl[base_xd + (long)l*RP + 80 + n]);
    float dA = __expf(dtc*An);
    hs = dA*hs + (dtc*xc)*Bc;
    float ys = hs * Cc;
    ys += __shfl_xor(ys, 1, 64);
    ys += __shfl_xor(ys, 2, 64);
    ys += __shfl_xor(ys, 4, 64);
    ys += __shfl_xor(ys, 8, 64);
    if (n == 0){
      long o = base + (long)l*EE;
      float zv = b2f(zy[o]);
      float g = zv / (1.f + __expf(-zv));
      zy[o] = f2b((ys + xc*Dv) * g);
    }
  }
}

extern "C" void kernel_launch(void* const* d_in, const int* in_sizes, int n_in,
                              void* d_out, int out_size, void* d_ws, size_t ws_size,
                              hipStream_t stream) {
  const float* x       = (const float*)d_in[0];
  const float* ln_w    = (const float*)d_in[1];
  const float* ln_b    = (const float*)d_in[2];
  const float* w_in_f  = (const float*)d_in[3];
  const float* conv_w  = (const float*)d_in[4];
  const float* conv_b  = (const float*)d_in[5];
  const float* w_xp_f  = (const float*)d_in[6];
  const float* w_dt_f  = (const float*)d_in[7];
  const float* dt_bias = (const float*)d_in[8];
  const float* A_log   = (const float*)d_in[9];
  const float* Dp      = (const float*)d_in[10];
  const float* w_out_f = (const float*)d_in[11];
  float* out = (float*)d_out;

  // Workspace layout (177 MiB total; lifetimes annotated):
  char* p = (char*)d_ws;
  bf16* h_bf  = (bf16*)p; p += (size_t)16384*1024*2;   // 32 MiB  [ln -> in_proj]; then S+Hinit
  bf16* xraw  = (bf16*)p; p += (size_t)16384*2048*2;   // 64 MiB  [in_proj -> conv]; then dt
  bf16* zbuf  = (bf16*)p; p += (size_t)16384*2048*2;   // 64 MiB  [in_proj -> scan]; y written in-place
  bf16* xdbl  = (bf16*)p; p += (size_t)16384*128*2;    // 4 MiB   [x_proj -> scan]
  bf16* w_in  = (bf16*)p; p += (size_t)4096*1024*2;    // 8 MiB   [cast -> in_proj]; then sdt
  bf16* w_xp  = (bf16*)p; p += (size_t)128*2048*2;     // 0.5 MiB
  bf16* w_dt  = (bf16*)p; p += (size_t)2048*64*2;      // 0.25 MiB
  bf16* w_out = (bf16*)p; p += (size_t)1024*2048*2;    // 4 MiB
  bf16* dt    = xraw;                                   // alias: xraw dead after conv
  bf16* xm    = (bf16*)d_out;                           // 64 MiB scratch in d_out (dead before out_proj)
  float* S     = (float*)h_bf;                          // 16 MiB (B*NC*E*16 fp32), h_bf dead after in_proj
  float* Hinit = S + (size_t)8*NC*EE*16;                // 16 MiB
  float* sdt   = (float*)w_in;                          // 1 MiB, w_in dead after in_proj

  // weight casts
  cast_kernel<<<16384,256,0,stream>>>(w_in_f,  w_in, 4096*1024);
  cast_kernel<<<512,  256,0,stream>>>(w_dt_f,  w_dt, 2048*64);
  cast_kernel<<<8192, 256,0,stream>>>(w_out_f, w_out, 1024*2048);
  pad_xproj_kernel<<<1024,256,0,stream>>>(w_xp_f, w_xp);

  // layernorm
  ln_kernel<<<16384,256,0,stream>>>(x, ln_w, ln_b, h_bf);

  // in_proj: (16384x1024) x (4096x1024)^T -> xraw (cols<2048) + zbuf (cols>=2048)
  gemm_bt<3><<<dim3(32,128),256,0,stream>>>(h_bf,1024, w_in,1024, xraw,EE, 1024, nullptr, nullptr,0, zbuf);

  // conv + silu -> xm (in d_out)
  conv_silu_kernel<<<131072,256,0,stream>>>(xraw, conv_w, conv_b, xm);

  // x_proj: (16384x2048) x (128x2048)^T -> xdbl bf16 (padded)
  gemm_bt<0><<<dim3(1,128),256,0,stream>>>(xm,2048, w_xp,2048, xdbl,RP, 2048, nullptr, nullptr,0, nullptr);

  // dt_proj + softplus: (16384x64) x (2048x64)^T -> dt (overlays xraw)
  gemm_bt<1><<<dim3(16,128),256,0,stream>>>(xdbl,RP, w_dt,64, dt,EE, 64, dt_bias, nullptr,0, nullptr);

  // chunked selective scan
  scan_pass1<<<dim3(128,NC,8),256,0,stream>>>(dt, xm, xdbl, A_log, S, sdt);
  scan_pass2<<<1024,256,0,stream>>>(S, sdt, A_log, Hinit);
  scan_pass3<<<dim3(128,NC,8),256,0,stream>>>(dt, xm, xdbl, zbuf, A_log, Dp, Hinit);

  // out_proj + residual: (16384x2048) x (1024x2048)^T + x -> out fp32
  gemm_bt<2><<<dim3(8,128),256,0,stream>>>(zbuf,2048, w_out,2048, out,1024, 2048, nullptr, x,1024, nullptr);
}

// Round 4
// 1371.460 us; speedup vs baseline: 1.8398x; 1.5712x over previous
//
#include <hip/hip_runtime.h>
#include <hip/hip_bf16.h>

// Mamba block: B=8 L=2048 D_MODEL=1024 D_INNER=2048 D_STATE=16 D_CONV=4 DT_RANK=64
#define LB 2048
#define DM 1024
#define EE 2048
#define RP 128   // x_dbl padded width (64 dt_r + 16 B + 16 C + 32 pad)
#define CH 128   // scan chunk length
#define NC 16    // LB/CH chunks

typedef __attribute__((ext_vector_type(8))) short bf16x8;
typedef __attribute__((ext_vector_type(4))) float f32x4;
using bf16 = __hip_bfloat16;

__device__ __forceinline__ float b2f(bf16 v){ return __bfloat162float(v); }
__device__ __forceinline__ bf16 f2b(float v){ return __float2bfloat16(v); }
__device__ __forceinline__ float us2f(short u){ return __uint_as_float(((unsigned)(unsigned short)u) << 16); }

// ---------------- cast helpers ----------------
__global__ void cast_kernel(const float* __restrict__ s, bf16* __restrict__ d, int n){
  int i = blockIdx.x*256 + threadIdx.x;
  int st = gridDim.x*256;
  for(; i<n; i+=st) d[i] = f2b(s[i]);
}

__global__ void pad_xproj_kernel(const float* __restrict__ s, bf16* __restrict__ d){
  int i = blockIdx.x*256 + threadIdx.x;  // over 128*2048
  int row = i >> 11;
  int col = i & 2047;
  float v = (row < 96) ? s[row*2048 + col] : 0.f;
  d[i] = f2b(v);
}

// ---------------- layernorm -> bf16 ----------------
__device__ __forceinline__ float wave_sum(float v){
  #pragma unroll
  for (int m=32;m>=1;m>>=1) v += __shfl_xor(v, m, 64);
  return v;
}

__global__ __launch_bounds__(256) void ln_kernel(const float* __restrict__ x,
                                                 const float* __restrict__ w,
                                                 const float* __restrict__ bb,
                                                 bf16* __restrict__ h){
  long row = blockIdx.x;
  const float4* xr = (const float4*)(x + row*DM);
  float4 v = xr[threadIdx.x];
  float s1 = v.x+v.y+v.z+v.w;
  float s2 = v.x*v.x+v.y*v.y+v.z*v.z+v.w*v.w;
  __shared__ float sm1[4], sm2[4];
  float w1 = wave_sum(s1), w2 = wave_sum(s2);
  int wid = threadIdx.x>>6, lane = threadIdx.x&63;
  if (lane==0){ sm1[wid]=w1; sm2[wid]=w2; }
  __syncthreads();
  float t1 = sm1[0]+sm1[1]+sm1[2]+sm1[3];
  float t2 = sm2[0]+sm2[1]+sm2[2]+sm2[3];
  float mean = t1 * (1.f/(float)DM);
  float var  = t2 * (1.f/(float)DM) - mean*mean;
  float rs = rsqrtf(var + 1e-5f);
  float4 wv = ((const float4*)w)[threadIdx.x];
  float4 bv = ((const float4*)bb)[threadIdx.x];
  int col = threadIdx.x*4;
  bf16 tmp[4];
  tmp[0] = f2b((v.x-mean)*rs*wv.x + bv.x);
  tmp[1] = f2b((v.y-mean)*rs*wv.y + bv.y);
  tmp[2] = f2b((v.z-mean)*rs*wv.z + bv.z);
  tmp[3] = f2b((v.w-mean)*rs*wv.w + bv.w);
  *(ushort4*)(h + row*DM + col) = *(ushort4*)tmp;
}

// ---------------- GEMM: C(MxN) = A(MxK) * Bw(NxK)^T, bf16 in, fp32 acc ----------------
// MODE 0: store bf16.
// MODE 1: softplus(acc+bias[col]) -> bf16.
// MODE 2: acc+resid -> fp32.
// MODE 3: split store: col<2048 -> Cout, else Cout2 (both bf16, ld 2048)
template<int MODE>
__global__ __launch_bounds__(256) void gemm_bt(
  const bf16* __restrict__ A, int lda,
  const bf16* __restrict__ Bw, int ldb,
  void* __restrict__ Cout, int ldc,
  int K,
  const float* __restrict__ bias,
  const float* __restrict__ resid, int ldr,
  void* __restrict__ Cout2)
{
  int wid  = threadIdx.x >> 6;
  int lane = threadIdx.x & 63;
  int wr = wid >> 1, wc = wid & 1;           // 2x2 waves -> 128x128 block tile
  int bm = blockIdx.y*128 + wr*64;
  int bn = blockIdx.x*128 + wc*64;
  int lm = lane & 15;                         // row within fragment
  int kg = lane >> 4;                         // k-group, k offset kg*8
  f32x4 acc[4][4] = {};
  const bf16* Ab = A  + (long)(bm+lm)*lda + kg*8;
  const bf16* Bb = Bw + (long)(bn+lm)*ldb + kg*8;
  for (int k0 = 0; k0 < K; k0 += 32){
    bf16x8 a[4], b[4];
    #pragma unroll
    for (int i=0;i<4;i++) a[i] = *(const bf16x8*)(Ab + (long)i*16*lda + k0);
    #pragma unroll
    for (int j=0;j<4;j++) b[j] = *(const bf16x8*)(Bb + (long)j*16*ldb + k0);
    #pragma unroll
    for (int i=0;i<4;i++)
      #pragma unroll
      for (int j=0;j<4;j++)
        acc[i][j] = __builtin_amdgcn_mfma_f32_16x16x32_bf16(a[i], b[j], acc[i][j], 0,0,0);
  }
  #pragma unroll
  for (int i=0;i<4;i++)
    #pragma unroll
    for (int j=0;j<4;j++)
      #pragma unroll
      for (int r=0;r<4;r++){
        int row = bm + i*16 + kg*4 + r;
        int col = bn + j*16 + lm;
        float v = acc[i][j][r];
        if constexpr (MODE==0){
          ((bf16*)Cout)[(long)row*ldc + col] = f2b(v);
        } else if constexpr (MODE==1){
          float t = v + bias[col];
          float sp = (t > 15.f) ? t : log1pf(__expf(t));
          ((bf16*)Cout)[(long)row*ldc + col] = f2b(sp);
        } else if constexpr (MODE==2){
          ((float*)Cout)[(long)row*ldc + col] = v + resid[(long)row*ldr + col];
        } else {
          if (col < EE) ((bf16*)Cout )[(long)row*EE + col]      = f2b(v);
          else          ((bf16*)Cout2)[(long)row*EE + col - EE] = f2b(v);
        }
      }
}

// ---------------- depthwise causal conv(4) + SiLU ----------------
__global__ __launch_bounds__(256) void conv_silu_kernel(
  const bf16* __restrict__ xraw,   // (B,L,E)
  const float* __restrict__ cw,    // (E,1,4)
  const float* __restrict__ cb,    // (E)
  bf16* __restrict__ out)          // (B,L,E)
{
  long idx = (long)blockIdx.x*256 + threadIdx.x;   // over 8*2048*2048
  int e = idx & (EE-1);
  long bl = idx >> 11;
  int l = bl & (LB-1);
  long b = bl >> 11;
  float acc = cb[e];
  #pragma unroll
  for (int k=0;k<4;k++){
    int ls = l - 3 + k;
    if (ls >= 0)
      acc += b2f(xraw[((b*LB)+ls)*EE + e]) * cw[e*4 + k];
  }
  float s = acc / (1.f + __expf(-acc));
  out[idx] = f2b(s);
}

// ---------------- chunked selective scan ----------------
// Mapping: one thread owns one (b, chunk, e) and carries all 16 n-states in registers.
// B (and C for pass3) rows for the chunk are staged to LDS as f32 (broadcast reads).

// Pass 1: chunk-local state S (h0=0) and sum(dt).
__global__ __launch_bounds__(256) void scan_pass1(
  const bf16* __restrict__ dt,     // (B,L,E)
  const bf16* __restrict__ xm,     // (B,L,E)
  const bf16* __restrict__ xdbl,   // (B,L,128): cols [64,80)=B
  const float* __restrict__ A_log, // (E,16)
  float* __restrict__ S,           // (B,NC,E,16)
  float* __restrict__ sdt)         // (B,NC,E)
{
  __shared__ float ldsB[CH][16];
  int t = threadIdx.x;
  int e = blockIdx.x*256 + t;
  int c = blockIdx.y;
  int b = blockIdx.z;
  // stage B rows: 128 rows x 16 bf16; thread t loads row t>>1, 8 elems at (t&1)*8
  {
    int row = t >> 1, part = (t & 1) * 8;
    long src = ((long)b*LB + (long)c*CH + row)*RP + 64 + part;
    bf16x8 v = *(const bf16x8*)(xdbl + src);
    #pragma unroll
    for (int i=0;i<8;i++) ldsB[row][part+i] = us2f(v[i]);
  }
  __syncthreads();

  float An[16], h[16];
  #pragma unroll
  for (int q=0;q<4;q++){
    f32x4 a = *(const f32x4*)(A_log + (long)e*16 + q*4);
    #pragma unroll
    for (int r=0;r<4;r++){ An[q*4+r] = -__expf(a[r]); h[q*4+r] = 0.f; }
  }
  float sd = 0.f;
  long base = ((long)b*LB + (long)c*CH)*EE + e;
  for (int l = 0; l < CH; ++l){
    float dtc = b2f(dt[base + (long)l*EE]);
    float xc  = b2f(xm[base + (long)l*EE]);
    float du = dtc*xc;
    sd += dtc;
    f32x4 B0 = *(const f32x4*)&ldsB[l][0];
    f32x4 B1 = *(const f32x4*)&ldsB[l][4];
    f32x4 B2 = *(const f32x4*)&ldsB[l][8];
    f32x4 B3 = *(const f32x4*)&ldsB[l][12];
    #pragma unroll
    for (int n=0;n<16;n++){
      float Bv = (n<4)? B0[n&3] : (n<8)? B1[n&3] : (n<12)? B2[n&3] : B3[n&3];
      float dA = __expf(An[n]*dtc);
      h[n] = dA*h[n] + du*Bv;
    }
  }
  long ci = ((long)b*NC + c)*EE + e;
  #pragma unroll
  for (int q=0;q<4;q++){
    f32x4 v = { h[q*4+0], h[q*4+1], h[q*4+2], h[q*4+3] };
    *(f32x4*)(S + ci*16 + q*4) = v;
  }
  sdt[ci] = sd;
}

// Pass 2: sequential scan over the NC chunk summaries; store exclusive prefix Hinit.
__global__ __launch_bounds__(256) void scan_pass2(
  const float* __restrict__ S,
  const float* __restrict__ sdt,
  const float* __restrict__ A_log,
  float* __restrict__ Hinit)       // (B,NC,E,16)
{
  int t = blockIdx.x*256 + threadIdx.x;   // over 8*2048*16
  int n = t & 15;
  int e = (t >> 4) & (EE-1);
  int b = t >> 15;
  float An = -expf(A_log[e*16 + n]);
  float H = 0.f;
  for (int c = 0; c < NC; ++c){
    long ci = ((long)b*NC + c)*EE + e;
    Hinit[ci*16 + n] = H;
    H = __expf(An * sdt[ci]) * H + S[ci*16 + n];
  }
}

// Pass 3: replay chunk seeded with Hinit; emit y (gated, in-place over z).
__global__ __launch_bounds__(256) void scan_pass3(
  const bf16* __restrict__ dt,
  const bf16* __restrict__ xm,
  const bf16* __restrict__ xdbl,   // cols [64,80)=B, [80,96)=C
  bf16* zy,                        // in z, out y (in-place, same pointer)
  const float* __restrict__ A_log,
  const float* __restrict__ Dp,
  const float* __restrict__ Hinit)
{
  __shared__ float ldsB[CH][16];
  __shared__ float ldsC[CH][16];
  int t = threadIdx.x;
  int e = blockIdx.x*256 + t;
  int c = blockIdx.y;
  int b = blockIdx.z;
  // stage B+C rows: 128 rows x 32 bf16; thread t loads row t>>1, 16 elems at (t&1)*16
  {
    int row = t >> 1, half = (t & 1);        // half 0 -> B, 1 -> C
    long src = ((long)b*LB + (long)c*CH + row)*RP + 64 + half*16;
    bf16x8 v0 = *(const bf16x8*)(xdbl + src);
    bf16x8 v1 = *(const bf16x8*)(xdbl + src + 8);
    float* dst = half ? &ldsC[row][0] : &ldsB[row][0];
    #pragma unroll
    for (int i=0;i<8;i++) dst[i]   = us2f(v0[i]);
    #pragma unroll
    for (int i=0;i<8;i++) dst[8+i] = us2f(v1[i]);
  }
  __syncthreads();

  float An[16], h[16];
  long ci = ((long)b*NC + c)*EE + e;
  #pragma unroll
  for (int q=0;q<4;q++){
    f32x4 a  = *(const f32x4*)(A_log + (long)e*16 + q*4);
    f32x4 hv = *(const f32x4*)(Hinit + ci*16 + q*4);
    #pragma unroll
    for (int r=0;r<4;r++){ An[q*4+r] = -__expf(a[r]); h[q*4+r] = hv[r]; }
  }
  float Dv = Dp[e];
  long base = ((long)b*LB + (long)c*CH)*EE + e;
  for (int l = 0; l < CH; ++l){
    float dtc = b2f(dt[base + (long)l*EE]);
    float xc  = b2f(xm[base + (long)l*EE]);
    float du = dtc*xc;
    f32x4 B0 = *(const f32x4*)&ldsB[l][0];
    f32x4 B1 = *(const f32x4*)&ldsB[l][4];
    f32x4 B2 = *(const f32x4*)&ldsB[l][8];
    f32x4 B3 = *(const f32x4*)&ldsB[l][12];
    f32x4 C0 = *(const f32x4*)&ldsC[l][0];
    f32x4 C1 = *(const f32x4*)&ldsC[l][4];
    f32x4 C2 = *(const f32x4*)&ldsC[l][8];
    f32x4 C3 = *(const f32x4*)&ldsC[l][12];
    float ys = 0.f;
    #pragma unroll
    for (int n=0;n<16;n++){
      float Bv = (n<4)? B0[n&3] : (n<8)? B1[n&3] : (n<12)? B2[n&3] : B3[n&3];
      float Cv = (n<4)? C0[n&3] : (n<8)? C1[n&3] : (n<12)? C2[n&3] : C3[n&3];
      float dA = __expf(An[n]*dtc);
      h[n] = dA*h[n] + du*Bv;
      ys += h[n]*Cv;
    }
    long o = base + (long)l*EE;
    float zv = b2f(zy[o]);
    float g = zv / (1.f + __expf(-zv));
    zy[o] = f2b((ys + xc*Dv) * g);
  }
}

extern "C" void kernel_launch(void* const* d_in, const int* in_sizes, int n_in,
                              void* d_out, int out_size, void* d_ws, size_t ws_size,
                              hipStream_t stream) {
  const float* x       = (const float*)d_in[0];
  const float* ln_w    = (const float*)d_in[1];
  const float* ln_b    = (const float*)d_in[2];
  const float* w_in_f  = (const float*)d_in[3];
  const float* conv_w  = (const float*)d_in[4];
  const float* conv_b  = (const float*)d_in[5];
  const float* w_xp_f  = (const float*)d_in[6];
  const float* w_dt_f  = (const float*)d_in[7];
  const float* dt_bias = (const float*)d_in[8];
  const float* A_log   = (const float*)d_in[9];
  const float* Dp      = (const float*)d_in[10];
  const float* w_out_f = (const float*)d_in[11];
  float* out = (float*)d_out;

  // Workspace layout (177 MiB total; lifetimes annotated):
  char* p = (char*)d_ws;
  bf16* h_bf  = (bf16*)p; p += (size_t)16384*1024*2;   // 32 MiB  [ln -> in_proj]; then S+Hinit
  bf16* xraw  = (bf16*)p; p += (size_t)16384*2048*2;   // 64 MiB  [in_proj -> conv]; then dt
  bf16* zbuf  = (bf16*)p; p += (size_t)16384*2048*2;   // 64 MiB  [in_proj -> scan]; y written in-place
  bf16* xdbl  = (bf16*)p; p += (size_t)16384*128*2;    // 4 MiB   [x_proj -> scan]
  bf16* w_in  = (bf16*)p; p += (size_t)4096*1024*2;    // 8 MiB   [cast -> in_proj]; then sdt
  bf16* w_xp  = (bf16*)p; p += (size_t)128*2048*2;     // 0.5 MiB
  bf16* w_dt  = (bf16*)p; p += (size_t)2048*64*2;      // 0.25 MiB
  bf16* w_out = (bf16*)p; p += (size_t)1024*2048*2;    // 4 MiB
  bf16* dt    = xraw;                                   // alias: xraw dead after conv
  bf16* xm    = (bf16*)d_out;                           // 64 MiB scratch in d_out (dead before out_proj)
  float* S     = (float*)h_bf;                          // 16 MiB, h_bf dead after in_proj
  float* Hinit = S + (size_t)8*NC*EE*16;                // 16 MiB
  float* sdt   = (float*)w_in;                          // 1 MiB, w_in dead after in_proj

  // weight casts
  cast_kernel<<<16384,256,0,stream>>>(w_in_f,  w_in, 4096*1024);
  cast_kernel<<<512,  256,0,stream>>>(w_dt_f,  w_dt, 2048*64);
  cast_kernel<<<8192, 256,0,stream>>>(w_out_f, w_out, 1024*2048);
  pad_xproj_kernel<<<1024,256,0,stream>>>(w_xp_f, w_xp);

  // layernorm
  ln_kernel<<<16384,256,0,stream>>>(x, ln_w, ln_b, h_bf);

  // in_proj: (16384x1024) x (4096x1024)^T -> xraw (cols<2048) + zbuf (cols>=2048)
  gemm_bt<3><<<dim3(32,128),256,0,stream>>>(h_bf,1024, w_in,1024, xraw,EE, 1024, nullptr, nullptr,0, zbuf);

  // conv + silu -> xm (in d_out)
  conv_silu_kernel<<<131072,256,0,stream>>>(xraw, conv_w, conv_b, xm);

  // x_proj: (16384x2048) x (128x2048)^T -> xdbl bf16 (padded)
  gemm_bt<0><<<dim3(1,128),256,0,stream>>>(xm,2048, w_xp,2048, xdbl,RP, 2048, nullptr, nullptr,0, nullptr);

  // dt_proj + softplus: (16384x64) x (2048x64)^T -> dt (overlays xraw)
  gemm_bt<1><<<dim3(16,128),256,0,stream>>>(xdbl,RP, w_dt,64, dt,EE, 64, dt_bias, nullptr,0, nullptr);

  // chunked selective scan (one thread per (b,c,e), 16 states in registers)
  scan_pass1<<<dim3(8,NC,8),256,0,stream>>>(dt, xm, xdbl, A_log, S, sdt);
  scan_pass2<<<1024,256,0,stream>>>(S, sdt, A_log, Hinit);
  scan_pass3<<<dim3(8,NC,8),256,0,stream>>>(dt, xm, xdbl, zbuf, A_log, Dp, Hinit);

  // out_proj + residual: (16384x2048) x (1024x2048)^T + x -> out fp32
  gemm_bt<2><<<dim3(8,128),256,0,stream>>>(zbuf,2048, w_out,2048, out,1024, 2048, nullptr, x,1024, nullptr);
}

// Round 5
// 949.403 us; speedup vs baseline: 2.6577x; 1.4445x over previous
//
#include <hip/hip_runtime.h>
#include <hip/hip_bf16.h>

// Mamba block: B=8 L=2048 D_MODEL=1024 D_INNER=2048 D_STATE=16 D_CONV=4 DT_RANK=64
#define LB 2048
#define DM 1024
#define EE 2048
#define RP 128   // x_dbl padded width (64 dt_r + 16 B + 16 C + 32 pad)
#define CH 128   // scan chunk length
#define NC 16    // LB/CH chunks

typedef __attribute__((ext_vector_type(8))) short bf16x8;
typedef __attribute__((ext_vector_type(4))) float f32x4;
using bf16 = __hip_bfloat16;

__device__ __forceinline__ float b2f(bf16 v){ return __bfloat162float(v); }
__device__ __forceinline__ bf16 f2b(float v){ return __float2bfloat16(v); }
__device__ __forceinline__ float us2f(short u){ return __uint_as_float(((unsigned)(unsigned short)u) << 16); }

// async global->LDS, 16B per lane. LDS dest must be linear in lane order (wave-uniform base + lane*16).
__device__ __forceinline__ void gload16(const bf16* g, bf16* l){
  __builtin_amdgcn_global_load_lds(
    (const __attribute__((address_space(1))) void*)g,
    (__attribute__((address_space(3))) void*)l, 16, 0, 0);
}

// ---------------- cast helpers ----------------
__global__ void cast_kernel(const float* __restrict__ s, bf16* __restrict__ d, int n){
  int i = blockIdx.x*256 + threadIdx.x;
  int st = gridDim.x*256;
  for(; i<n; i+=st) d[i] = f2b(s[i]);
}

__global__ void pad_xproj_kernel(const float* __restrict__ s, bf16* __restrict__ d){
  int i = blockIdx.x*256 + threadIdx.x;  // over 128*2048
  int row = i >> 11;
  int col = i & 2047;
  float v = (row < 96) ? s[row*2048 + col] : 0.f;
  d[i] = f2b(v);
}

// ---------------- layernorm -> bf16 ----------------
__device__ __forceinline__ float wave_sum(float v){
  #pragma unroll
  for (int m=32;m>=1;m>>=1) v += __shfl_xor(v, m, 64);
  return v;
}

__global__ __launch_bounds__(256) void ln_kernel(const float* __restrict__ x,
                                                 const float* __restrict__ w,
                                                 const float* __restrict__ bb,
                                                 bf16* __restrict__ h){
  long row = blockIdx.x;
  const float4* xr = (const float4*)(x + row*DM);
  float4 v = xr[threadIdx.x];
  float s1 = v.x+v.y+v.z+v.w;
  float s2 = v.x*v.x+v.y*v.y+v.z*v.z+v.w*v.w;
  __shared__ float sm1[4], sm2[4];
  float w1 = wave_sum(s1), w2 = wave_sum(s2);
  int wid = threadIdx.x>>6, lane = threadIdx.x&63;
  if (lane==0){ sm1[wid]=w1; sm2[wid]=w2; }
  __syncthreads();
  float t1 = sm1[0]+sm1[1]+sm1[2]+sm1[3];
  float t2 = sm2[0]+sm2[1]+sm2[2]+sm2[3];
  float mean = t1 * (1.f/(float)DM);
  float var  = t2 * (1.f/(float)DM) - mean*mean;
  float rs = rsqrtf(var + 1e-5f);
  float4 wv = ((const float4*)w)[threadIdx.x];
  float4 bv = ((const float4*)bb)[threadIdx.x];
  int col = threadIdx.x*4;
  bf16 tmp[4];
  tmp[0] = f2b((v.x-mean)*rs*wv.x + bv.x);
  tmp[1] = f2b((v.y-mean)*rs*wv.y + bv.y);
  tmp[2] = f2b((v.z-mean)*rs*wv.z + bv.z);
  tmp[3] = f2b((v.w-mean)*rs*wv.w + bv.w);
  *(ushort4*)(h + row*DM + col) = *(ushort4*)tmp;
}

// ---------------- GEMM: C(MxN) = A(MxK) * Bw(NxK)^T, bf16 in, fp32 acc ----------------
// m97 structure: 128x128 tile, BK=32, global_load_lds(16B) -> linear LDS, 2-barrier loop.
// MODE 0: store bf16.
// MODE 1: softplus(acc+bias[col]) -> bf16.
// MODE 2: acc+resid -> fp32.
// MODE 3: split store: col<2048 -> Cout, else Cout2 (both bf16, ld 2048)
template<int MODE>
__global__ __launch_bounds__(256) void gemm_bt(
  const bf16* __restrict__ A, int lda,
  const bf16* __restrict__ Bw, int ldb,
  void* __restrict__ Cout, int ldc,
  int K,
  const float* __restrict__ bias,
  const float* __restrict__ resid, int ldr,
  void* __restrict__ Cout2)
{
  __shared__ __align__(16) bf16 ldsA[128*32];
  __shared__ __align__(16) bf16 ldsB[128*32];
  int t = threadIdx.x;
  int wid  = t >> 6;
  int lane = t & 63;
  int wr = wid >> 1, wc = wid & 1;           // 2x2 waves -> 128x128 block tile
  int bm = blockIdx.y*128 + wr*64;
  int bn = blockIdx.x*128 + wc*64;
  int lm = lane & 15;                         // row within fragment
  int kg = lane >> 4;                         // k-group, k offset kg*8
  f32x4 acc[4][4] = {};

  // staging: thread t covers LDS elems [t*8, t*8+8) of each 128x32 tile half.
  // t*8 = row*32 + col8*8 -> row = t>>2 (0..63), col8 = t&3
  int srow = t >> 2;
  int scol = (t & 3) * 8;
  const bf16* Ag0 = A  + (long)(blockIdx.y*128 + srow)*lda + scol;
  const bf16* Ag1 = Ag0 + (long)64*lda;
  const bf16* Bg0 = Bw + (long)(blockIdx.x*128 + srow)*ldb + scol;
  const bf16* Bg1 = Bg0 + (long)64*ldb;
  bf16* lA0 = ldsA + t*8;
  bf16* lA1 = ldsA + 2048 + t*8;
  bf16* lB0 = ldsB + t*8;
  bf16* lB1 = ldsB + 2048 + t*8;
  // fragment LDS elem offsets
  int aoff = (wr*64 + lm)*32 + kg*8;
  int boff = (wc*64 + lm)*32 + kg*8;

  for (int k0 = 0; k0 < K; k0 += 32){
    gload16(Ag0 + k0, lA0);
    gload16(Ag1 + k0, lA1);
    gload16(Bg0 + k0, lB0);
    gload16(Bg1 + k0, lB1);
    __syncthreads();                          // compiler drains vmcnt before barrier
    bf16x8 a[4], b[4];
    #pragma unroll
    for (int i=0;i<4;i++) a[i] = *(const bf16x8*)(ldsA + aoff + i*16*32);
    #pragma unroll
    for (int j=0;j<4;j++) b[j] = *(const bf16x8*)(ldsB + boff + j*16*32);
    #pragma unroll
    for (int i=0;i<4;i++)
      #pragma unroll
      for (int j=0;j<4;j++)
        acc[i][j] = __builtin_amdgcn_mfma_f32_16x16x32_bf16(a[i], b[j], acc[i][j], 0,0,0);
    __syncthreads();
  }

  #pragma unroll
  for (int i=0;i<4;i++)
    #pragma unroll
    for (int j=0;j<4;j++)
      #pragma unroll
      for (int r=0;r<4;r++){
        int row = bm + i*16 + kg*4 + r;
        int col = bn + j*16 + lm;
        float v = acc[i][j][r];
        if constexpr (MODE==0){
          ((bf16*)Cout)[(long)row*ldc + col] = f2b(v);
        } else if constexpr (MODE==1){
          float tt = v + bias[col];
          float sp = (tt > 15.f) ? tt : log1pf(__expf(tt));
          ((bf16*)Cout)[(long)row*ldc + col] = f2b(sp);
        } else if constexpr (MODE==2){
          ((float*)Cout)[(long)row*ldc + col] = v + resid[(long)row*ldr + col];
        } else {
          if (col < EE) ((bf16*)Cout )[(long)row*EE + col]      = f2b(v);
          else          ((bf16*)Cout2)[(long)row*EE + col - EE] = f2b(v);
        }
      }
}

// ---------------- depthwise causal conv(4) + SiLU ----------------
__global__ __launch_bounds__(256) void conv_silu_kernel(
  const bf16* __restrict__ xraw,   // (B,L,E)
  const float* __restrict__ cw,    // (E,1,4)
  const float* __restrict__ cb,    // (E)
  bf16* __restrict__ out)          // (B,L,E)
{
  long idx = (long)blockIdx.x*256 + threadIdx.x;   // over 8*2048*2048
  int e = idx & (EE-1);
  long bl = idx >> 11;
  int l = bl & (LB-1);
  long b = bl >> 11;
  float acc = cb[e];
  #pragma unroll
  for (int k=0;k<4;k++){
    int ls = l - 3 + k;
    if (ls >= 0)
      acc += b2f(xraw[((b*LB)+ls)*EE + e]) * cw[e*4 + k];
  }
  float s = acc / (1.f + __expf(-acc));
  out[idx] = f2b(s);
}

// ---------------- chunked selective scan ----------------
// Mapping: one thread owns one (b, chunk, e) and carries all 16 n-states in registers.
// B (and C for pass3) rows for the chunk are staged to LDS as f32 (broadcast reads).

// Pass 1: chunk-local state S (h0=0) and sum(dt).
__global__ __launch_bounds__(256) void scan_pass1(
  const bf16* __restrict__ dt,     // (B,L,E)
  const bf16* __restrict__ xm,     // (B,L,E)
  const bf16* __restrict__ xdbl,   // (B,L,128): cols [64,80)=B
  const float* __restrict__ A_log, // (E,16)
  float* __restrict__ S,           // (B,NC,E,16)
  float* __restrict__ sdt)         // (B,NC,E)
{
  __shared__ float ldsB[CH][16];
  int t = threadIdx.x;
  int e = blockIdx.x*256 + t;
  int c = blockIdx.y;
  int b = blockIdx.z;
  {
    int row = t >> 1, part = (t & 1) * 8;
    long src = ((long)b*LB + (long)c*CH + row)*RP + 64 + part;
    bf16x8 v = *(const bf16x8*)(xdbl + src);
    #pragma unroll
    for (int i=0;i<8;i++) ldsB[row][part+i] = us2f(v[i]);
  }
  __syncthreads();

  float An[16], h[16];
  #pragma unroll
  for (int q=0;q<4;q++){
    f32x4 a = *(const f32x4*)(A_log + (long)e*16 + q*4);
    #pragma unroll
    for (int r=0;r<4;r++){ An[q*4+r] = -__expf(a[r]); h[q*4+r] = 0.f; }
  }
  float sd = 0.f;
  long base = ((long)b*LB + (long)c*CH)*EE + e;
  for (int l = 0; l < CH; ++l){
    float dtc = b2f(dt[base + (long)l*EE]);
    float xc  = b2f(xm[base + (long)l*EE]);
    float du = dtc*xc;
    sd += dtc;
    f32x4 B0 = *(const f32x4*)&ldsB[l][0];
    f32x4 B1 = *(const f32x4*)&ldsB[l][4];
    f32x4 B2 = *(const f32x4*)&ldsB[l][8];
    f32x4 B3 = *(const f32x4*)&ldsB[l][12];
    #pragma unroll
    for (int n=0;n<16;n++){
      float Bv = (n<4)? B0[n&3] : (n<8)? B1[n&3] : (n<12)? B2[n&3] : B3[n&3];
      float dA = __expf(An[n]*dtc);
      h[n] = dA*h[n] + du*Bv;
    }
  }
  long ci = ((long)b*NC + c)*EE + e;
  #pragma unroll
  for (int q=0;q<4;q++){
    f32x4 v = { h[q*4+0], h[q*4+1], h[q*4+2], h[q*4+3] };
    *(f32x4*)(S + ci*16 + q*4) = v;
  }
  sdt[ci] = sd;
}

// Pass 2: sequential scan over the NC chunk summaries; store exclusive prefix Hinit.
__global__ __launch_bounds__(256) void scan_pass2(
  const float* __restrict__ S,
  const float* __restrict__ sdt,
  const float* __restrict__ A_log,
  float* __restrict__ Hinit)       // (B,NC,E,16)
{
  int t = blockIdx.x*256 + threadIdx.x;   // over 8*2048*16
  int n = t & 15;
  int e = (t >> 4) & (EE-1);
  int b = t >> 15;
  float An = -expf(A_log[e*16 + n]);
  float H = 0.f;
  for (int c = 0; c < NC; ++c){
    long ci = ((long)b*NC + c)*EE + e;
    Hinit[ci*16 + n] = H;
    H = __expf(An * sdt[ci]) * H + S[ci*16 + n];
  }
}

// Pass 3: replay chunk seeded with Hinit; emit y (gated, in-place over z).
__global__ __launch_bounds__(256) void scan_pass3(
  const bf16* __restrict__ dt,
  const bf16* __restrict__ xm,
  const bf16* __restrict__ xdbl,   // cols [64,80)=B, [80,96)=C
  bf16* zy,                        // in z, out y (in-place, same pointer)
  const float* __restrict__ A_log,
  const float* __restrict__ Dp,
  const float* __restrict__ Hinit)
{
  __shared__ float ldsB[CH][16];
  __shared__ float ldsC[CH][16];
  int t = threadIdx.x;
  int e = blockIdx.x*256 + t;
  int c = blockIdx.y;
  int b = blockIdx.z;
  {
    int row = t >> 1, half = (t & 1);        // half 0 -> B, 1 -> C
    long src = ((long)b*LB + (long)c*CH + row)*RP + 64 + half*16;
    bf16x8 v0 = *(const bf16x8*)(xdbl + src);
    bf16x8 v1 = *(const bf16x8*)(xdbl + src + 8);
    float* dst = half ? &ldsC[row][0] : &ldsB[row][0];
    #pragma unroll
    for (int i=0;i<8;i++) dst[i]   = us2f(v0[i]);
    #pragma unroll
    for (int i=0;i<8;i++) dst[8+i] = us2f(v1[i]);
  }
  __syncthreads();

  float An[16], h[16];
  long ci = ((long)b*NC + c)*EE + e;
  #pragma unroll
  for (int q=0;q<4;q++){
    f32x4 a  = *(const f32x4*)(A_log + (long)e*16 + q*4);
    f32x4 hv = *(const f32x4*)(Hinit + ci*16 + q*4);
    #pragma unroll
    for (int r=0;r<4;r++){ An[q*4+r] = -__expf(a[r]); h[q*4+r] = hv[r]; }
  }
  float Dv = Dp[e];
  long base = ((long)b*LB + (long)c*CH)*EE + e;
  for (int l = 0; l < CH; ++l){
    float dtc = b2f(dt[base + (long)l*EE]);
    float xc  = b2f(xm[base + (long)l*EE]);
    float du = dtc*xc;
    f32x4 B0 = *(const f32x4*)&ldsB[l][0];
    f32x4 B1 = *(const f32x4*)&ldsB[l][4];
    f32x4 B2 = *(const f32x4*)&ldsB[l][8];
    f32x4 B3 = *(const f32x4*)&ldsB[l][12];
    f32x4 C0 = *(const f32x4*)&ldsC[l][0];
    f32x4 C1 = *(const f32x4*)&ldsC[l][4];
    f32x4 C2 = *(const f32x4*)&ldsC[l][8];
    f32x4 C3 = *(const f32x4*)&ldsC[l][12];
    float ys = 0.f;
    #pragma unroll
    for (int n=0;n<16;n++){
      float Bv = (n<4)? B0[n&3] : (n<8)? B1[n&3] : (n<12)? B2[n&3] : B3[n&3];
      float Cv = (n<4)? C0[n&3] : (n<8)? C1[n&3] : (n<12)? C2[n&3] : C3[n&3];
      float dA = __expf(An[n]*dtc);
      h[n] = dA*h[n] + du*Bv;
      ys += h[n]*Cv;
    }
    long o = base + (long)l*EE;
    float zv = b2f(zy[o]);
    float g = zv / (1.f + __expf(-zv));
    zy[o] = f2b((ys + xc*Dv) * g);
  }
}

extern "C" void kernel_launch(void* const* d_in, const int* in_sizes, int n_in,
                              void* d_out, int out_size, void* d_ws, size_t ws_size,
                              hipStream_t stream) {
  const float* x       = (const float*)d_in[0];
  const float* ln_w    = (const float*)d_in[1];
  const float* ln_b    = (const float*)d_in[2];
  const float* w_in_f  = (const float*)d_in[3];
  const float* conv_w  = (const float*)d_in[4];
  const float* conv_b  = (const float*)d_in[5];
  const float* w_xp_f  = (const float*)d_in[6];
  const float* w_dt_f  = (const float*)d_in[7];
  const float* dt_bias = (const float*)d_in[8];
  const float* A_log   = (const float*)d_in[9];
  const float* Dp      = (const float*)d_in[10];
  const float* w_out_f = (const float*)d_in[11];
  float* out = (float*)d_out;

  // Workspace layout (177 MiB total; lifetimes annotated):
  char* p = (char*)d_ws;
  bf16* h_bf  = (bf16*)p; p += (size_t)16384*1024*2;   // 32 MiB  [ln -> in_proj]; then S+Hinit
  bf16* xraw  = (bf16*)p; p += (size_t)16384*2048*2;   // 64 MiB  [in_proj -> conv]; then dt
  bf16* zbuf  = (bf16*)p; p += (size_t)16384*2048*2;   // 64 MiB  [in_proj -> scan]; y written in-place
  bf16* xdbl  = (bf16*)p; p += (size_t)16384*128*2;    // 4 MiB   [x_proj -> scan]
  bf16* w_in  = (bf16*)p; p += (size_t)4096*1024*2;    // 8 MiB   [cast -> in_proj]; then sdt
  bf16* w_xp  = (bf16*)p; p += (size_t)128*2048*2;     // 0.5 MiB
  bf16* w_dt  = (bf16*)p; p += (size_t)2048*64*2;      // 0.25 MiB
  bf16* w_out = (bf16*)p; p += (size_t)1024*2048*2;    // 4 MiB
  bf16* dt    = xraw;                                   // alias: xraw dead after conv
  bf16* xm    = (bf16*)d_out;                           // 64 MiB scratch in d_out (dead before out_proj)
  float* S     = (float*)h_bf;                          // 16 MiB, h_bf dead after in_proj
  float* Hinit = S + (size_t)8*NC*EE*16;                // 16 MiB
  float* sdt   = (float*)w_in;                          // 1 MiB, w_in dead after in_proj

  // weight casts
  cast_kernel<<<16384,256,0,stream>>>(w_in_f,  w_in, 4096*1024);
  cast_kernel<<<512,  256,0,stream>>>(w_dt_f,  w_dt, 2048*64);
  cast_kernel<<<8192, 256,0,stream>>>(w_out_f, w_out, 1024*2048);
  pad_xproj_kernel<<<1024,256,0,stream>>>(w_xp_f, w_xp);

  // layernorm
  ln_kernel<<<16384,256,0,stream>>>(x, ln_w, ln_b, h_bf);

  // in_proj: (16384x1024) x (4096x1024)^T -> xraw (cols<2048) + zbuf (cols>=2048)
  gemm_bt<3><<<dim3(32,128),256,0,stream>>>(h_bf,1024, w_in,1024, xraw,EE, 1024, nullptr, nullptr,0, zbuf);

  // conv + silu -> xm (in d_out)
  conv_silu_kernel<<<131072,256,0,stream>>>(xraw, conv_w, conv_b, xm);

  // x_proj: (16384x2048) x (128x2048)^T -> xdbl bf16 (padded)
  gemm_bt<0><<<dim3(1,128),256,0,stream>>>(xm,2048, w_xp,2048, xdbl,RP, 2048, nullptr, nullptr,0, nullptr);

  // dt_proj + softplus: (16384x64) x (2048x64)^T -> dt (overlays xraw)
  gemm_bt<1><<<dim3(16,128),256,0,stream>>>(xdbl,RP, w_dt,64, dt,EE, 64, dt_bias, nullptr,0, nullptr);

  // chunked selective scan (one thread per (b,c,e), 16 states in registers)
  scan_pass1<<<dim3(8,NC,8),256,0,stream>>>(dt, xm, xdbl, A_log, S, sdt);
  scan_pass2<<<1024,256,0,stream>>>(S, sdt, A_log, Hinit);
  scan_pass3<<<dim3(8,NC,8),256,0,stream>>>(dt, xm, xdbl, zbuf, A_log, Dp, Hinit);

  // out_proj + residual: (16384x2048) x (1024x2048)^T + x -> out fp32
  gemm_bt<2><<<dim3(8,128),256,0,stream>>>(zbuf,2048, w_out,2048, out,1024, 2048, nullptr, x,1024, nullptr);
}